// Round 2
// baseline (1388.549 us; speedup 1.0000x reference)
//
#include <hip/hip_runtime.h>
#include <stdint.h>

#define M_DIM 2048
#define N_DIM 4096
#define K_DIM 11008
#define NN    11008
#define KTOK  2201    // int(11008*0.2)
#define NSEL  4403    // int(11008*0.4)
#define NCHUNK 43     // 43*256 == 11008
#define NBINS 2049    // counts in [0,2048]
#define NWORDS 344    // 11008/32 mask words per row

typedef __bf16 bf16x8_t __attribute__((ext_vector_type(8)));
typedef float  f32x4_t  __attribute__((ext_vector_type(4)));

__device__ __forceinline__ unsigned short f2bf(float f) {
  unsigned u = __float_as_uint(f);
  u = (u + 0x7FFFu + ((u >> 16) & 1u)) >> 16;   // round-to-nearest-even
  return (unsigned short)u;
}

// ---------------- f32 -> bf16 conversion (vectorized) ----------------
__global__ __launch_bounds__(256) void cvt_f32_bf16(const float4* __restrict__ src,
                                                    ushort4* __restrict__ dst, int n4) {
  int i = blockIdx.x * 256 + threadIdx.x;
  int stride = gridDim.x * 256;
  for (; i < n4; i += stride) {
    float4 v = src[i];
    ushort4 o;
    o.x = f2bf(v.x); o.y = f2bf(v.y); o.z = f2bf(v.z); o.w = f2bf(v.w);
    dst[i] = o;
  }
}

// ---------------- per-row top-KTOK -> per-row bitmask (radix select in LDS) ---------
// No global atomics: each row writes 344 mask words to maskT[word][row].
__global__ __launch_bounds__(256) void topk_rows(const float* __restrict__ x,
                                                 unsigned* __restrict__ maskT) {
  __shared__ unsigned keys[NN];     // 44032 B
  __shared__ int hist[2048];        // 8192 B
  __shared__ int csum[256];
  __shared__ unsigned mask[NWORDS]; // 1376 B
  __shared__ unsigned s_band;
  __shared__ int s_kneed;
  __shared__ int s_eqcnt;

  const int t = threadIdx.x;
  const int r = blockIdx.x;
  const float4* row4 = (const float4*)(x + (size_t)r * NN);

  for (int i = t; i < NWORDS; i += 256) mask[i] = 0u;
  for (int i = t; i < NN / 4; i += 256) {
    float4 v = row4[i];
    unsigned b0 = __float_as_uint(v.x), b1 = __float_as_uint(v.y);
    unsigned b2 = __float_as_uint(v.z), b3 = __float_as_uint(v.w);
    keys[4*i+0] = b0 ^ ((unsigned)((int)b0 >> 31) | 0x80000000u);
    keys[4*i+1] = b1 ^ ((unsigned)((int)b1 >> 31) | 0x80000000u);
    keys[4*i+2] = b2 ^ ((unsigned)((int)b2 >> 31) | 0x80000000u);
    keys[4*i+3] = b3 ^ ((unsigned)((int)b3 >> 31) | 0x80000000u);
  }
  __syncthreads();

  unsigned band_prefix = 0;
  int kneed = KTOK;

  for (int pass = 0; pass < 3; ++pass) {
    const int shift = (pass == 0) ? 21 : (pass == 1) ? 10 : 0;
    const int bins  = (pass == 2) ? 1024 : 2048;
    const unsigned mk = bins - 1;

    for (int i = t; i < bins; i += 256) hist[i] = 0;
    __syncthreads();

    for (int i = t; i < NN; i += 256) {
      unsigned k = keys[i];
      bool in_band;
      if (pass == 0)      in_band = true;
      else if (pass == 1) in_band = ((k >> 21) == band_prefix);
      else                in_band = ((k >> 10) == band_prefix);
      if (in_band) atomicAdd(&hist[(k >> shift) & mk], 1);
    }
    __syncthreads();

    const int nch = bins / 8;
    if (t < nch) {
      int s = 0;
      for (int v = t * 8; v < t * 8 + 8; ++v) s += hist[v];
      csum[t] = s;
    }
    __syncthreads();
    if (t == 0) {
      int run = 0; int b = 0;
      for (int tc = nch - 1; tc >= 0; --tc) {
        if (run + csum[tc] >= kneed) {
          for (int v = tc * 8 + 7;; --v) {
            if (run + hist[v] >= kneed) { b = v; break; }
            run += hist[v];
          }
          break;
        }
        run += csum[tc];
      }
      s_band = (unsigned)b;
      s_kneed = kneed - run;   // >=1: how many to take from band b
    }
    __syncthreads();
    band_prefix = (pass == 0) ? s_band
                : (band_prefix << ((pass == 1) ? 11 : 10)) | s_band;
    kneed = s_kneed;
    __syncthreads();
  }

  const unsigned Tkey = band_prefix;   // exact KTOK-th largest key
  const int need = kneed;              // # equal-to-threshold to take (lowest idx)

  if (t == 0) s_eqcnt = 0;
  __syncthreads();
  for (int i = t; i < NN; i += 256) {
    unsigned k = keys[i];
    if (k > Tkey) atomicOr(&mask[i >> 5], 1u << (i & 31));
    else if (k == Tkey) atomicAdd(&s_eqcnt, 1);
  }
  __syncthreads();
  const int eq = s_eqcnt;
  if (eq == need) {   // common case
    for (int i = t; i < NN; i += 256)
      if (keys[i] == Tkey) atomicOr(&mask[i >> 5], 1u << (i & 31));
  } else if (t == 0) { // rare boundary tie: take lowest indices
    int taken = 0;
    for (int i = 0; i < NN && taken < need; ++i)
      if (keys[i] == Tkey) { mask[i >> 5] |= 1u << (i & 31); ++taken; }
  }
  __syncthreads();

  for (int w = t; w < NWORDS; w += 256)
    maskT[(size_t)w * M_DIM + r] = mask[w];
}

// ---------------- bit-count votes: counts[n] = sum_r maskT bit ----------------
// 344 blocks; block w handles neurons w*32..w*32+31 across all 2048 rows.
__global__ __launch_bounds__(256) void count_votes(const unsigned* __restrict__ maskT,
                                                   int* __restrict__ counts) {
  __shared__ int part[256 * 33];   // padded stride 33 -> conflict-free
  const int t = threadIdx.x;
  const int w = blockIdx.x;
  int c[32];
#pragma unroll
  for (int b = 0; b < 32; ++b) c[b] = 0;
  const unsigned* col = maskT + (size_t)w * M_DIM;
#pragma unroll
  for (int rep = 0; rep < M_DIM / 256; ++rep) {
    unsigned m = col[rep * 256 + t];
#pragma unroll
    for (int b = 0; b < 32; ++b) c[b] += (m >> b) & 1u;
  }
#pragma unroll
  for (int b = 0; b < 32; ++b) part[t * 33 + b] = c[b];
  __syncthreads();
  if (t < 32) {
    int s = 0;
    for (int j = 0; j < 256; ++j) s += part[j * 33 + t];
    counts[w * 32 + t] = s;
  }
}

// ---------------- stable counting sort of counts (desc value, asc index) ----------------
__global__ __launch_bounds__(256) void count_hist(const int* __restrict__ counts,
                                                  int* __restrict__ bhist,
                                                  int* __restrict__ rnk) {
  __shared__ int lc[256];
  __shared__ int lh[NBINS];
  const int b = blockIdx.x, t = threadIdx.x;
  const int n = b * 256 + t;
  const int c = counts[n];
  lc[t] = c;
  for (int i = t; i < NBINS; i += 256) lh[i] = 0;
  __syncthreads();
  atomicAdd(&lh[c], 1);
  __syncthreads();
  for (int i = t; i < NBINS; i += 256) bhist[b * NBINS + i] = lh[i];
  int rk = 0;
  for (int m = 0; m < t; ++m) rk += (lc[m] == c);
  rnk[n] = rk;
}

__global__ __launch_bounds__(256) void scan_hist(const int* __restrict__ bhist,
                                                 int* __restrict__ pre) {
  __shared__ int total[NBINS];
  __shared__ int sstart[NBINS];
  const int t = threadIdx.x;
  for (int c = t; c < NBINS; c += 256) {
    int s = 0;
    for (int h = 0; h < NCHUNK; ++h) s += bhist[h * NBINS + c];
    total[c] = s;
  }
  __syncthreads();
  if (t == 0) {
    int run = 0;
    for (int c = NBINS - 1; c >= 0; --c) { sstart[c] = run; run += total[c]; }
  }
  __syncthreads();
  for (int c = t; c < NBINS; c += 256) {
    int run = sstart[c];
    for (int h = 0; h < NCHUNK; ++h) { pre[h * NBINS + c] = run; run += bhist[h * NBINS + c]; }
  }
}

__global__ __launch_bounds__(256) void place(const int* __restrict__ counts,
                                             const int* __restrict__ rnk,
                                             const int* __restrict__ pre,
                                             int* __restrict__ sel) {
  const int b = blockIdx.x, t = threadIdx.x;
  const int n = b * 256 + t;
  const int c = counts[n];
  const int pos = pre[b * NBINS + c] + rnk[n];
  if (pos < NSEL) sel[pos] = n;
}

// ---------------- gather filtered_W ----------------
__global__ __launch_bounds__(256) void gather_w(const float* __restrict__ w,
                                                const int* __restrict__ sel,
                                                float* __restrict__ out) {
  const int j = blockIdx.x * 256 + threadIdx.x;
  const int d = blockIdx.y;
  if (j < NSEL) out[(size_t)d * NSEL + j] = w[(size_t)d * NN + sel[j]];
}

// ---------------- bf16 MFMA GEMM: C[M][N] = A[M][K] * B[N][K]^T ----------------
#define BM 128
#define BN 128
#define BK 32

__device__ __forceinline__ void async16(const void* g, void* l) {
  __builtin_amdgcn_global_load_lds(
      (const __attribute__((address_space(1))) void*)g,
      (__attribute__((address_space(3))) void*)l, 16, 0, 0);
}

__global__ __launch_bounds__(256) void gemm_bt(const unsigned short* __restrict__ A,
                                               const unsigned short* __restrict__ B,
                                               float* __restrict__ C) {
  __shared__ unsigned short As[BM * BK];   // 8 KB
  __shared__ unsigned short Bs[BN * BK];   // 8 KB
  const int t = threadIdx.x;
  const int lane = t & 63;
  const int wave = t >> 6;
  const int wm = wave >> 1, wn = wave & 1;
  const int m0 = blockIdx.y * BM;
  const int n0 = blockIdx.x * BN;

  f32x4_t acc[4][4];
#pragma unroll
  for (int i = 0; i < 4; ++i)
#pragma unroll
    for (int j = 0; j < 4; ++j) acc[i][j] = (f32x4_t){0.f, 0.f, 0.f, 0.f};

  // staging: 512 chunks of 16B per tile; thread t handles chunks t and t+256
  const int row0 = t >> 2,        kc0 = t & 3;
  const int row1 = (t + 256) >> 2, kc1 = t & 3;   // (t+256)&3 == t&3
  char* asb0 = (char*)As + (t & ~63) * 16;
  char* asb1 = (char*)As + ((t & ~63) + 256) * 16;
  char* bsb0 = (char*)Bs + (t & ~63) * 16;
  char* bsb1 = (char*)Bs + ((t & ~63) + 256) * 16;

  const unsigned short* Ab = A + (size_t)m0 * K_DIM;
  const unsigned short* Bb = B + (size_t)n0 * K_DIM;

  for (int kk = 0; kk < K_DIM; kk += BK) {
    async16(Ab + (size_t)row0 * K_DIM + kk + kc0 * 8, asb0);
    async16(Ab + (size_t)row1 * K_DIM + kk + kc1 * 8, asb1);
    async16(Bb + (size_t)row0 * K_DIM + kk + kc0 * 8, bsb0);
    async16(Bb + (size_t)row1 * K_DIM + kk + kc1 * 8, bsb1);
    __syncthreads();

    bf16x8_t af[4], bf[4];
#pragma unroll
    for (int i = 0; i < 4; ++i)
      af[i] = *(const bf16x8_t*)&As[(wm * 64 + i * 16 + (lane & 15)) * BK + (lane >> 4) * 8];
#pragma unroll
    for (int j = 0; j < 4; ++j)
      bf[j] = *(const bf16x8_t*)&Bs[(wn * 64 + j * 16 + (lane & 15)) * BK + (lane >> 4) * 8];
#pragma unroll
    for (int i = 0; i < 4; ++i)
#pragma unroll
      for (int j = 0; j < 4; ++j)
        acc[i][j] = __builtin_amdgcn_mfma_f32_16x16x32_bf16(af[i], bf[j], acc[i][j], 0, 0, 0);
    __syncthreads();
  }

  // epilogue: C/D layout col=lane&15, row=(lane>>4)*4+reg
#pragma unroll
  for (int i = 0; i < 4; ++i) {
    const int rbase = m0 + wm * 64 + i * 16 + (lane >> 4) * 4;
#pragma unroll
    for (int j = 0; j < 4; ++j) {
      const int col = n0 + wn * 64 + j * 16 + (lane & 15);
#pragma unroll
      for (int rr = 0; rr < 4; ++rr)
        C[(size_t)(rbase + rr) * N_DIM + col] = acc[i][j][rr];
    }
  }
}

// ---------------- launcher ----------------
extern "C" void kernel_launch(void* const* d_in, const int* in_sizes, int n_in,
                              void* d_out, int out_size, void* d_ws, size_t ws_size,
                              hipStream_t stream) {
  const float* x = (const float*)d_in[0];   // [1,2048,11008]
  const float* w = (const float*)d_in[1];   // [4096,11008]
  float* out = (float*)d_out;
  float* true_val = out;                                // 2048*4096
  float* filt = out + (size_t)M_DIM * N_DIM;            // 4096*4403

  // workspace layout (~136.1 MB)
  char* ws = (char*)d_ws;
  unsigned short* xb = (unsigned short*)ws;                       // 45,088,768 B
  unsigned short* wb = (unsigned short*)(ws + 45088768);          // 90,177,536 B
  int* counts = (int*)(ws + 45088768 + 90177536);                 // 44,032 B
  int* rnk    = counts + NN;                                      // 44,032 B
  int* bhist  = rnk + NN;                                         // 43*2049*4 B
  int* pre    = bhist + NCHUNK * NBINS;                           // 43*2049*4 B
  int* sel    = pre + NCHUNK * NBINS;                             // 17,612 B

  // vote bitmask (344*2048 u32 = 2.8 MB) staged in the true_value output
  // region, which gemm_bt fully overwrites afterwards.
  unsigned* maskT = (unsigned*)true_val;

  cvt_f32_bf16<<<4096, 256, 0, stream>>>((const float4*)x, (ushort4*)xb, M_DIM * K_DIM / 4);
  cvt_f32_bf16<<<4096, 256, 0, stream>>>((const float4*)w, (ushort4*)wb, N_DIM * K_DIM / 4);

  topk_rows<<<M_DIM, 256, 0, stream>>>(x, maskT);
  count_votes<<<NWORDS, 256, 0, stream>>>(maskT, counts);
  count_hist<<<NCHUNK, 256, 0, stream>>>(counts, bhist, rnk);
  scan_hist<<<1, 256, 0, stream>>>(bhist, pre);
  place<<<NCHUNK, 256, 0, stream>>>(counts, rnk, pre, sel);
  gather_w<<<dim3((NSEL + 255) / 256, N_DIM), 256, 0, stream>>>(w, sel, filt);

  gemm_bt<<<dim3(N_DIM / BN, M_DIM / BM), 256, 0, stream>>>(xb, wb, true_val);
}

// Round 3
// 960.103 us; speedup vs baseline: 1.4462x; 1.4462x over previous
//
#include <hip/hip_runtime.h>
#include <stdint.h>

#define M_DIM 2048
#define N_DIM 4096
#define K_DIM 11008
#define NN    11008
#define KTOK  2201    // int(11008*0.2)
#define NSEL  4403    // int(11008*0.4)
#define NCHUNK 43     // 43*256 == 11008
#define NBINS 2049    // counts in [0,2048]
#define NWORDS 344    // 11008/32 mask words per row
#define NC64  172     // 11008/64 ballot chunks per row

typedef __bf16 bf16x8_t __attribute__((ext_vector_type(8)));
typedef float  f32x4_t  __attribute__((ext_vector_type(4)));

__device__ __forceinline__ unsigned short f2bf(float f) {
  unsigned u = __float_as_uint(f);
  u = (u + 0x7FFFu + ((u >> 16) & 1u)) >> 16;   // round-to-nearest-even
  return (unsigned short)u;
}

// ---------------- f32 -> bf16 conversion (vectorized) ----------------
__global__ __launch_bounds__(256) void cvt_f32_bf16(const float4* __restrict__ src,
                                                    ushort4* __restrict__ dst, int n4) {
  int i = blockIdx.x * 256 + threadIdx.x;
  int stride = gridDim.x * 256;
  for (; i < n4; i += stride) {
    float4 v = src[i];
    ushort4 o;
    o.x = f2bf(v.x); o.y = f2bf(v.y); o.z = f2bf(v.z); o.w = f2bf(v.w);
    dst[i] = o;
  }
}

// ---------------- per-row top-KTOK -> per-row bitmask (radix select in LDS) ---------
// All-parallel: suffix-scan bin select (no serial t==0 walk), ballot-built masks
// (no LDS atomics), exact stable tie handling via ballot ranks.
__global__ __launch_bounds__(256) void topk_rows(const float* __restrict__ x,
                                                 unsigned* __restrict__ maskT) {
  __shared__ unsigned keys[NN];     // 44032 B
  __shared__ int hist[2048];        // 8192 B
  __shared__ int wtot[4];
  __shared__ int eqpre[NC64];       // 688 B  (per-chunk eq counts)
  __shared__ int eqex[NC64];        // 688 B  (exclusive prefix)
  __shared__ unsigned s_band;
  __shared__ int s_kneed;

  const int t = threadIdx.x;
  const int lane = t & 63;
  const int w = t >> 6;
  const int r = blockIdx.x;

  // ---- load row, transform to order-preserving u32 keys ----
  const uint4* row4 = (const uint4*)(x + (size_t)r * NN);
  for (int i = t; i < NN / 4; i += 256) {
    uint4 v = row4[i];
    uint4 kv;
    kv.x = v.x ^ ((unsigned)((int)v.x >> 31) | 0x80000000u);
    kv.y = v.y ^ ((unsigned)((int)v.y >> 31) | 0x80000000u);
    kv.z = v.z ^ ((unsigned)((int)v.z >> 31) | 0x80000000u);
    kv.w = v.w ^ ((unsigned)((int)v.w >> 31) | 0x80000000u);
    ((uint4*)keys)[i] = kv;
  }
  __syncthreads();

  // ---- 3-pass radix select for the KTOK-th largest key ----
  unsigned band_prefix = 0;
  int kneed = KTOK;

  for (int pass = 0; pass < 3; ++pass) {
    const int shift = (pass == 0) ? 21 : (pass == 1) ? 10 : 0;
    const int bins  = (pass == 2) ? 1024 : 2048;
    const unsigned mk = bins - 1;

    for (int i = t; i < bins; i += 256) hist[i] = 0;
    __syncthreads();

    for (int i = t; i < NN; i += 256) {
      unsigned k = keys[i];
      bool in_band;
      if (pass == 0)      in_band = true;
      else if (pass == 1) in_band = ((k >> 21) == band_prefix);
      else                in_band = ((k >> 10) == band_prefix);
      if (in_band) atomicAdd(&hist[(k >> shift) & mk], 1);
    }
    __syncthreads();

    // parallel suffix-select: thread t owns 8 bins [8t, 8t+8)
    const int nch = bins / 8;      // 256 (passes 0,1) or 128 (pass 2)
    const int nw  = nch >> 6;      // active waves in the scan
    int loc = 0;
    if (t < nch) {
#pragma unroll
      for (int v = 0; v < 8; ++v) loc += hist[t * 8 + v];
    }
    // within-wave inclusive suffix sum (whole wave participates)
    int incl = loc;
#pragma unroll
    for (int d = 1; d < 64; d <<= 1) {
      int o = __shfl_down(incl, d);
      if (lane + d < 64) incl += o;
    }
    if (w < nw && lane == 0) wtot[w] = incl;
    __syncthreads();
    int wsuf = 0;
    for (int u = w + 1; u < nw; ++u) wsuf += wtot[u];
    const int suf_ex = wsuf + (incl - loc);   // sum of bins strictly above chunk t
    if (t < nch && suf_ex < kneed && suf_ex + loc >= kneed) {
      int run = suf_ex;
      for (int v = t * 8 + 7;; --v) {
        int h = hist[v];
        if (run + h >= kneed) { s_band = (unsigned)v; s_kneed = kneed - run; break; }
        run += h;
      }
    }
    __syncthreads();
    band_prefix = (pass == 0) ? s_band
                : (band_prefix << ((pass == 1) ? 11 : 10)) | s_band;
    kneed = s_kneed;
    __syncthreads();
  }

  const unsigned Tkey = band_prefix;   // exact KTOK-th largest key
  const int need = kneed;              // # equal-to-Tkey to take (lowest index first)

  // ---- per-chunk equal counts (ballot), then exclusive prefix ----
  for (int c = w; c < NC64; c += 4) {
    unsigned k = keys[c * 64 + lane];
    unsigned long long eb = __ballot(k == Tkey);
    if (lane == 0) eqpre[c] = __popcll(eb);
  }
  __syncthreads();
  if (t < NC64) {
    int s = 0;
    for (int c = 0; c < t; ++c) s += eqpre[c];   // independent reads, pipelined
    eqex[t] = s;
  }
  __syncthreads();

  // ---- build mask words via ballot; stable tie-break toward lowest index ----
  for (int c = w; c < NC64; c += 4) {
    unsigned k = keys[c * 64 + lane];
    const bool eq = (k == Tkey);
    unsigned long long eb = __ballot(eq);
    int myrank = eqex[c] + __popcll(eb & ((1ull << lane) - 1ull));
    bool pred = (k > Tkey) || (eq && (myrank < need));
    unsigned long long pb = __ballot(pred);
    if (lane == 0) maskT[(size_t)(2 * c)     * M_DIM + r] = (unsigned)pb;
    if (lane == 1) maskT[(size_t)(2 * c + 1) * M_DIM + r] = (unsigned)(pb >> 32);
  }
}

// ---------------- bit-count votes: counts[n] = sum_r maskT bit ----------------
__global__ __launch_bounds__(256) void count_votes(const unsigned* __restrict__ maskT,
                                                   int* __restrict__ counts) {
  __shared__ int part[256 * 33];   // padded stride 33 -> conflict-free
  const int t = threadIdx.x;
  const int w = blockIdx.x;
  int c[32];
#pragma unroll
  for (int b = 0; b < 32; ++b) c[b] = 0;
  const unsigned* col = maskT + (size_t)w * M_DIM;
#pragma unroll
  for (int rep = 0; rep < M_DIM / 256; ++rep) {
    unsigned m = col[rep * 256 + t];
#pragma unroll
    for (int b = 0; b < 32; ++b) c[b] += (m >> b) & 1u;
  }
#pragma unroll
  for (int b = 0; b < 32; ++b) part[t * 33 + b] = c[b];
  __syncthreads();
  if (t < 32) {
    int s = 0;
    for (int j = 0; j < 256; ++j) s += part[j * 33 + t];
    counts[w * 32 + t] = s;
  }
}

// ---------------- stable counting sort of counts (desc value, asc index) ----------------
__global__ __launch_bounds__(256) void count_hist(const int* __restrict__ counts,
                                                  int* __restrict__ bhist,
                                                  int* __restrict__ rnk) {
  __shared__ int lc[256];
  __shared__ int lh[NBINS];
  const int b = blockIdx.x, t = threadIdx.x;
  const int n = b * 256 + t;
  const int c = counts[n];
  lc[t] = c;
  for (int i = t; i < NBINS; i += 256) lh[i] = 0;
  __syncthreads();
  atomicAdd(&lh[c], 1);
  __syncthreads();
  for (int i = t; i < NBINS; i += 256) bhist[b * NBINS + i] = lh[i];
  int rk = 0;
  for (int m = 0; m < t; ++m) rk += (lc[m] == c);
  rnk[n] = rk;
}

__global__ __launch_bounds__(256) void scan_hist(const int* __restrict__ bhist,
                                                 int* __restrict__ pre) {
  __shared__ int total[NBINS];
  __shared__ int sstart[NBINS];
  const int t = threadIdx.x;
  for (int c = t; c < NBINS; c += 256) {
    int s = 0;
    for (int h = 0; h < NCHUNK; ++h) s += bhist[h * NBINS + c];
    total[c] = s;
  }
  __syncthreads();
  if (t == 0) {
    int run = 0;
    for (int c = NBINS - 1; c >= 0; --c) { sstart[c] = run; run += total[c]; }
  }
  __syncthreads();
  for (int c = t; c < NBINS; c += 256) {
    int run = sstart[c];
    for (int h = 0; h < NCHUNK; ++h) { pre[h * NBINS + c] = run; run += bhist[h * NBINS + c]; }
  }
}

__global__ __launch_bounds__(256) void place(const int* __restrict__ counts,
                                             const int* __restrict__ rnk,
                                             const int* __restrict__ pre,
                                             int* __restrict__ sel) {
  const int b = blockIdx.x, t = threadIdx.x;
  const int n = b * 256 + t;
  const int c = counts[n];
  const int pos = pre[b * NBINS + c] + rnk[n];
  if (pos < NSEL) sel[pos] = n;
}

// ---------------- gather filtered_W ----------------
__global__ __launch_bounds__(256) void gather_w(const float* __restrict__ w,
                                                const int* __restrict__ sel,
                                                float* __restrict__ out) {
  const int j = blockIdx.x * 256 + threadIdx.x;
  const int d = blockIdx.y;
  if (j < NSEL) out[(size_t)d * NSEL + j] = w[(size_t)d * NN + sel[j]];
}

// ---------------- bf16 MFMA GEMM: C[M][N] = A[M][K] * B[N][K]^T ----------------
#define BM 128
#define BN 128
#define BK 32

__device__ __forceinline__ void async16(const void* g, void* l) {
  __builtin_amdgcn_global_load_lds(
      (const __attribute__((address_space(1))) void*)g,
      (__attribute__((address_space(3))) void*)l, 16, 0, 0);
}

__global__ __launch_bounds__(256) void gemm_bt(const unsigned short* __restrict__ A,
                                               const unsigned short* __restrict__ B,
                                               float* __restrict__ C) {
  __shared__ unsigned short As[BM * BK];   // 8 KB
  __shared__ unsigned short Bs[BN * BK];   // 8 KB
  const int t = threadIdx.x;
  const int lane = t & 63;
  const int wave = t >> 6;
  const int wm = wave >> 1, wn = wave & 1;
  const int m0 = blockIdx.y * BM;
  const int n0 = blockIdx.x * BN;

  f32x4_t acc[4][4];
#pragma unroll
  for (int i = 0; i < 4; ++i)
#pragma unroll
    for (int j = 0; j < 4; ++j) acc[i][j] = (f32x4_t){0.f, 0.f, 0.f, 0.f};

  const int row0 = t >> 2,        kc0 = t & 3;
  const int row1 = (t + 256) >> 2, kc1 = t & 3;
  char* asb0 = (char*)As + (t & ~63) * 16;
  char* asb1 = (char*)As + ((t & ~63) + 256) * 16;
  char* bsb0 = (char*)Bs + (t & ~63) * 16;
  char* bsb1 = (char*)Bs + ((t & ~63) + 256) * 16;

  const unsigned short* Ab = A + (size_t)m0 * K_DIM;
  const unsigned short* Bb = B + (size_t)n0 * K_DIM;

  for (int kk = 0; kk < K_DIM; kk += BK) {
    async16(Ab + (size_t)row0 * K_DIM + kk + kc0 * 8, asb0);
    async16(Ab + (size_t)row1 * K_DIM + kk + kc1 * 8, asb1);
    async16(Bb + (size_t)row0 * K_DIM + kk + kc0 * 8, bsb0);
    async16(Bb + (size_t)row1 * K_DIM + kk + kc1 * 8, bsb1);
    __syncthreads();

    bf16x8_t af[4], bf[4];
#pragma unroll
    for (int i = 0; i < 4; ++i)
      af[i] = *(const bf16x8_t*)&As[(wm * 64 + i * 16 + (lane & 15)) * BK + (lane >> 4) * 8];
#pragma unroll
    for (int j = 0; j < 4; ++j)
      bf[j] = *(const bf16x8_t*)&Bs[(wn * 64 + j * 16 + (lane & 15)) * BK + (lane >> 4) * 8];
#pragma unroll
    for (int i = 0; i < 4; ++i)
#pragma unroll
      for (int j = 0; j < 4; ++j)
        acc[i][j] = __builtin_amdgcn_mfma_f32_16x16x32_bf16(af[i], bf[j], acc[i][j], 0, 0, 0);
    __syncthreads();
  }

#pragma unroll
  for (int i = 0; i < 4; ++i) {
    const int rbase = m0 + wm * 64 + i * 16 + (lane >> 4) * 4;
#pragma unroll
    for (int j = 0; j < 4; ++j) {
      const int col = n0 + wn * 64 + j * 16 + (lane & 15);
#pragma unroll
      for (int rr = 0; rr < 4; ++rr)
        C[(size_t)(rbase + rr) * N_DIM + col] = acc[i][j][rr];
    }
  }
}

// ---------------- launcher ----------------
extern "C" void kernel_launch(void* const* d_in, const int* in_sizes, int n_in,
                              void* d_out, int out_size, void* d_ws, size_t ws_size,
                              hipStream_t stream) {
  const float* x = (const float*)d_in[0];   // [1,2048,11008]
  const float* w = (const float*)d_in[1];   // [4096,11008]
  float* out = (float*)d_out;
  float* true_val = out;                                // 2048*4096
  float* filt = out + (size_t)M_DIM * N_DIM;            // 4096*4403

  char* ws = (char*)d_ws;
  unsigned short* xb = (unsigned short*)ws;                       // 45,088,768 B
  unsigned short* wb = (unsigned short*)(ws + 45088768);          // 90,177,536 B
  int* counts = (int*)(ws + 45088768 + 90177536);                 // 44,032 B
  int* rnk    = counts + NN;                                      // 44,032 B
  int* bhist  = rnk + NN;                                         // 43*2049*4 B
  int* pre    = bhist + NCHUNK * NBINS;                           // 43*2049*4 B
  int* sel    = pre + NCHUNK * NBINS;                             // 17,612 B

  // vote bitmask (344*2048 u32 = 2.8 MB) staged in the true_value output
  // region, which gemm_bt fully overwrites afterwards.
  unsigned* maskT = (unsigned*)true_val;

  cvt_f32_bf16<<<4096, 256, 0, stream>>>((const float4*)x, (ushort4*)xb, M_DIM * K_DIM / 4);
  cvt_f32_bf16<<<4096, 256, 0, stream>>>((const float4*)w, (ushort4*)wb, N_DIM * K_DIM / 4);

  topk_rows<<<M_DIM, 256, 0, stream>>>(x, maskT);
  count_votes<<<NWORDS, 256, 0, stream>>>(maskT, counts);
  count_hist<<<NCHUNK, 256, 0, stream>>>(counts, bhist, rnk);
  scan_hist<<<1, 256, 0, stream>>>(bhist, pre);
  place<<<NCHUNK, 256, 0, stream>>>(counts, rnk, pre, sel);
  gather_w<<<dim3((NSEL + 255) / 256, N_DIM), 256, 0, stream>>>(w, sel, filt);

  gemm_bt<<<dim3(N_DIM / BN, M_DIM / BM), 256, 0, stream>>>(xb, wb, true_val);
}